// Round 7
// baseline (443.994 us; speedup 1.0000x reference)
//
#include <hip/hip_runtime.h>
#include <cstddef>
#include <cstdint>

typedef unsigned short ushort_t;
typedef unsigned int uint_t;
typedef __attribute__((ext_vector_type(8))) short short8;
typedef __attribute__((ext_vector_type(4))) float f32x4;

#define EDIM 1024
#define NHEAD 16
#define HDIM 64
#define NB 4
#define LQ 512
#define SK 1024
#define BHD 64

__device__ __forceinline__ ushort_t f2b(float f) {
    uint_t u = __float_as_uint(f);
    return (ushort_t)((u + 0x7fffu + ((u >> 16) & 1u)) >> 16);
}
__device__ __forceinline__ float b2f(ushort_t b) {
    return __uint_as_float(((uint_t)b) << 16);
}

__device__ __forceinline__ void gload_lds16(const void* g, void* l) {
    __builtin_amdgcn_global_load_lds((const __attribute__((address_space(1))) void*)g,
                                     (__attribute__((address_space(3))) void*)l, 16, 0, 0);
}

// ============ mega projection GEMM: all 5 jobs in one balanced launch ======
struct MegaArgs {
    const ushort_t *qx, *m1h, *m1l, *m2h, *m2l;
    const ushort_t *Wqg, *Wkv1, *Wkv2, *Wk1l, *Wk2l;
    const float *q_b, *k1_b, *k2_b, *v1_b, *v2_b, *g1_b, *g2_b;
    float *K1f, *K2f;
    ushort_t *V1b, *V2b, *Qb, *G1b, *G2b;
};

__global__ __launch_bounds__(256, 2)
void mega_gemm(MegaArgs a)
{
    __shared__ ushort_t As[128 * 64];
    __shared__ ushort_t Bs[128 * 64];
    const int tid = threadIdx.x;
    const int wave = tid >> 6, lane = tid & 63;
    const int ln = lane & 15, lq = lane >> 4;
    const int wm = wave & 1, wn = wave >> 1;
    const int cswz = (lane & 7) ^ ((lane >> 3) & 7);
    const int mrl = lane >> 3;

    const int id = blockIdx.x;
    const ushort_t *A, *Al, *B, *Bl;
    const float* bias;
    int npass, row0, col0, kind;
    if (id < 512) {  // K split-precision, long blocks first
        kind = id >> 8;
        const int t = id & 255;
        col0 = (t & 7) * 128; row0 = (t >> 3) * 128; npass = 3;
        A = kind ? a.m2h : a.m1h;  Al = kind ? a.m2l : a.m1l;
        B = kind ? a.Wkv2 : a.Wkv1; Bl = kind ? a.Wk2l : a.Wk1l;
        bias = kind ? a.k2_b : a.k1_b;
    } else if (id < 1024) {  // V
        int t = id - 512; kind = 2 + (t >> 8); t &= 255;
        col0 = (t & 7) * 128; row0 = (t >> 3) * 128; npass = 1;
        A = (kind == 2) ? a.m1h : a.m2h; Al = A;
        B = ((kind == 2) ? a.Wkv1 : a.Wkv2) + (size_t)1024 * 1024; Bl = B;
        bias = (kind == 2) ? a.v1_b : a.v2_b;
    } else {  // QG
        const int t = id - 1024; kind = 4;
        const int c = t % 24, rr = t / 24;
        col0 = c * 128; row0 = rr * 128; npass = 1;
        A = a.qx; Al = A; B = a.Wqg; Bl = B;
        const int seg = c >> 3;
        bias = (seg == 0) ? a.q_b : ((seg == 1) ? a.g1_b : a.g2_b);
    }

    f32x4 zero = {0.f, 0.f, 0.f, 0.f};
    f32x4 acc[4][4];
#pragma unroll
    for (int i = 0; i < 4; ++i)
#pragma unroll
        for (int j = 0; j < 4; ++j) acc[i][j] = zero;

    for (int pp = 0; pp < npass; ++pp) {
        const ushort_t* Ab = (pp == 2) ? Al : A;   // AhBh + AhBl + AlBh
        const ushort_t* Bb = (pp == 1) ? Bl : B;
        for (int kk = 0; kk < 1024; kk += 64) {
            __syncthreads();
#pragma unroll
            for (int j = 0; j < 4; ++j) {
                const int mr = (wave * 4 + j) * 8 + mrl;
                gload_lds16(Ab + (size_t)(row0 + mr) * 1024 + kk + cswz * 8,
                            (void*)(As + (wave * 4 + j) * 512));
                gload_lds16(Bb + (size_t)(col0 + mr) * 1024 + kk + cswz * 8,
                            (void*)(Bs + (wave * 4 + j) * 512));
            }
            __syncthreads();
#pragma unroll
            for (int sub = 0; sub < 2; ++sub) {
                short8 af[4], bfv[4];
#pragma unroll
                for (int i = 0; i < 4; ++i) {
                    const int ml = wm * 64 + i * 16 + ln;
                    af[i] = *(const short8*)(As + ml * 64 + (((sub * 4 + lq) ^ (ml & 7)) * 8));
                    const int nl = wn * 64 + i * 16 + ln;
                    bfv[i] = *(const short8*)(Bs + nl * 64 + (((sub * 4 + lq) ^ (nl & 7)) * 8));
                }
#pragma unroll
                for (int i = 0; i < 4; ++i)
#pragma unroll
                    for (int j = 0; j < 4; ++j)
                        acc[i][j] = __builtin_amdgcn_mfma_f32_16x16x32_bf16(af[i], bfv[j], acc[i][j], 0, 0, 0);
            }
        }
    }

#pragma unroll
    for (int i = 0; i < 4; ++i) {
#pragma unroll
        for (int r = 0; r < 4; ++r) {
            const int row = row0 + wm * 64 + i * 16 + lq * 4 + r;
#pragma unroll
            for (int j = 0; j < 4; ++j) {
                const int col = col0 + wn * 64 + j * 16 + ln;
                const int lc = col & 1023;
                float v = acc[i][j][r] + bias[lc];
                if (kind <= 1) {            // K fp32 head-split (S=1024)
                    const int s = row >> 2, b = row & 3, h = lc >> 6, d = lc & 63;
                    float* Y = kind ? a.K2f : a.K1f;
                    Y[(((size_t)(b * 16 + h)) * 1024 + s) * 64 + d] = v;
                } else if (kind <= 3) {     // V bf16 head-split
                    const int s = row >> 2, b = row & 3, h = lc >> 6, d = lc & 63;
                    ushort_t* Y = (kind == 2) ? a.V1b : a.V2b;
                    Y[(((size_t)(b * 16 + h)) * 1024 + s) * 64 + d] = f2b(v);
                } else {
                    const int seg = col >> 10;
                    if (seg == 0) {         // Q bf16 head-split (L=512), *scale
                        v *= 0.125f;
                        const int s = row >> 2, b = row & 3, h = lc >> 6, d = lc & 63;
                        a.Qb[(((size_t)(b * 16 + h)) * 512 + s) * 64 + d] = f2b(v);
                    } else {                // gates bf16 sigmoid flat
                        v = 1.0f / (1.0f + __expf(-v));
                        ushort_t* Y = (seg == 1) ? a.G1b : a.G2b;
                        Y[(size_t)row * 1024 + lc] = f2b(v);
                    }
                }
            }
        }
    }
}

// =============== fused input/weight casts (one launch) ===============
struct CastArgs {
    const float* q; const float* m1; const float* m2;
    ushort_t* qx; ushort_t* m1h; ushort_t* m1l; ushort_t* m2h; ushort_t* m2l;
    const float* wsrc[8];
    ushort_t* whi[8];
    ushort_t* wlo[8];
};

__global__ __launch_bounds__(256)
void casts_kernel(CastArgs a)
{
    __shared__ float T[64][65];
    const int id = blockIdx.x;
    const int tid = threadIdx.x;
    if (id < 1024) {                       // query cast
        const size_t i = ((size_t)id * 256 + tid) * 8;
        float4 x = *(const float4*)(a.q + i);
        float4 y = *(const float4*)(a.q + i + 4);
        ushort_t o[8] = {f2b(x.x), f2b(x.y), f2b(x.z), f2b(x.w), f2b(y.x), f2b(y.y), f2b(y.z), f2b(y.w)};
        *(uint4*)( (void*)(a.qx + i) ) = *(const uint4*)o;
    } else if (id < 5120) {                // mod hi/lo split casts
        const int t = id - 1024;
        const int which = t >> 11;
        const float* x = which ? a.m2 : a.m1;
        ushort_t* yh = which ? a.m2h : a.m1h;
        ushort_t* yl = which ? a.m2l : a.m1l;
        const size_t i = ((size_t)(t & 2047) * 256 + tid) * 8;
        float v[8];
        *(float4*)v = *(const float4*)(x + i);
        *(float4*)(v + 4) = *(const float4*)(x + i + 4);
        ushort_t oh[8], ol[8];
#pragma unroll
        for (int k = 0; k < 8; ++k) {
            oh[k] = f2b(v[k]);
            ol[k] = f2b(v[k] - b2f(oh[k]));
        }
        *(uint4*)( (void*)(yh + i) ) = *(const uint4*)oh;
        *(uint4*)( (void*)(yl + i) ) = *(const uint4*)ol;
    } else {                               // weight transpose+cast
        const int t = id - 5120;
        const int z = t >> 8, x = t & 15, y = (t >> 4) & 15;
        const float* W = a.wsrc[z];
        ushort_t* Th = a.whi[z];
        ushort_t* Tl = a.wlo[z];
        const int k0 = x * 64, n0 = y * 64;
        const int r = tid >> 2, cg = (tid & 3) * 16;
#pragma unroll
        for (int u = 0; u < 4; ++u) {
            float4 v = *(const float4*)(W + (size_t)(k0 + r) * 1024 + n0 + cg + u * 4);
            T[r][cg + u * 4 + 0] = v.x; T[r][cg + u * 4 + 1] = v.y;
            T[r][cg + u * 4 + 2] = v.z; T[r][cg + u * 4 + 3] = v.w;
        }
        __syncthreads();
        ushort_t oh[16], ol[16];
#pragma unroll
        for (int u = 0; u < 16; ++u) {
            float v = T[cg + u][r];
            oh[u] = f2b(v);
            ol[u] = f2b(v - b2f(oh[u]));
        }
        ushort_t* dh = Th + (size_t)(n0 + r) * 1024 + k0 + cg;
        *(uint4*)( (void*)dh ) = *(const uint4*)oh;
        *(uint4*)( (void*)(dh + 8) ) = *(const uint4*)(oh + 8);
        if (Tl) {
            ushort_t* dl = Tl + (size_t)(n0 + r) * 1024 + k0 + cg;
            *(uint4*)( (void*)dl ) = *(const uint4*)ol;
            *(uint4*)( (void*)(dl + 8) ) = *(const uint4*)(ol + 8);
        }
    }
}

// ====== fused prep: K norms+cast, Q norms, V transpose (one launch) ======
__global__ __launch_bounds__(256)
void prep_kernel(const float* __restrict__ K1f, const float* __restrict__ K2f,
                 ushort_t* __restrict__ K1b, ushort_t* __restrict__ K2b,
                 float* __restrict__ vv, float* __restrict__ aa, float* __restrict__ va,
                 const ushort_t* __restrict__ Qb, float* __restrict__ ll,
                 const ushort_t* __restrict__ V1b, const ushort_t* __restrict__ V2b,
                 ushort_t* __restrict__ V1t, ushort_t* __restrict__ V2t)
{
    __shared__ float T[64][65];
    const int id = blockIdx.x;
    const int tid = threadIdx.x;
    const int wave = tid >> 6, lane = tid & 63;
    if (id < 16384) {                      // K norms (fp32) + bf16 cast
        const int row = id * 4 + wave;
        const float x1 = K1f[(size_t)row * 64 + lane];
        const float x2 = K2f[(size_t)row * 64 + lane];
        K1b[(size_t)row * 64 + lane] = f2b(x1);
        K2b[(size_t)row * 64 + lane] = f2b(x2);
        float s1 = x1 * x1, s2 = x2 * x2, s3 = x1 * x2;
#pragma unroll
        for (int o = 1; o < 64; o <<= 1) {
            s1 += __shfl_xor(s1, o);
            s2 += __shfl_xor(s2, o);
            s3 += __shfl_xor(s3, o);
        }
        if (lane == 0) { vv[row] = s1; aa[row] = s2; va[row] = s3; }
    } else if (id < 24576) {               // Q norms
        const int row = (id - 16384) * 4 + wave;
        const float x = b2f(Qb[(size_t)row * 64 + lane]);
        float s = x * x;
#pragma unroll
        for (int o = 1; o < 64; o <<= 1) s += __shfl_xor(s, o);
        if (lane == 0) ll[row] = s;
    } else {                               // V transpose
        const int t = id - 24576;
        const int z = t >> 10, bh = (t >> 4) & 63, s0 = (t & 15) * 64;
        const ushort_t* S = z ? V2b : V1b;
        ushort_t* D = z ? V2t : V1t;
        const int r = tid >> 2, cg = (tid & 3) * 16;
        ushort_t buf[16];
        const ushort_t* sp = S + ((size_t)bh * 1024 + s0 + r) * 64 + cg;
        *(uint4*)buf = *(const uint4*)sp;
        *(uint4*)(buf + 8) = *(const uint4*)(sp + 8);
#pragma unroll
        for (int u = 0; u < 16; ++u) T[r][cg + u] = b2f(buf[u]);
        __syncthreads();
        ushort_t o[16];
#pragma unroll
        for (int u = 0; u < 16; ++u) o[u] = f2b(T[cg + u][r]);
        ushort_t* d = D + ((size_t)bh * 64 + r) * 1024 + s0 + cg;
        *(uint4*)( (void*)d ) = *(const uint4*)o;
        *(uint4*)( (void*)(d + 8) ) = *(const uint4*)(o + 8);
    }
}

// ======== flash attention: QK+gram -> online softmax -> p(bf16) -> PV =====
// grid (4 l-tiles, 64 bh), 512 threads. Two passes over 8 S-tiles of 128.
// Pass 1: logits recomputed, online row max/expsum (no logit storage).
// Pass 2: logits recomputed, p written (attn global + Ps LDS), PV MFMA,
//         gate epilogue -> tmpb.
__global__ __launch_bounds__(512, 1)
void flash_attn(const ushort_t* __restrict__ Qb, const ushort_t* __restrict__ K1b,
                const ushort_t* __restrict__ K2b, const ushort_t* __restrict__ V1t,
                const ushort_t* __restrict__ V2t, const float* __restrict__ ll,
                const float* __restrict__ vv, const float* __restrict__ aa,
                const float* __restrict__ va, const ushort_t* __restrict__ G1,
                const ushort_t* __restrict__ G2, ushort_t* __restrict__ attn,
                ushort_t* __restrict__ tmpb)
{
    __shared__ ushort_t Qs[128 * 64];
    __shared__ ushort_t K1s[128 * 64];
    __shared__ ushort_t K2s[128 * 64];
    __shared__ ushort_t V1s[64 * 128];
    __shared__ ushort_t V2s[64 * 128];
    __shared__ ushort_t Ps[128 * 128];
    __shared__ float vvS[1024], aaS[1024], vaS[1024];
    __shared__ float llS[128], mRow[128], sRow[128];
    __shared__ float redM[256], redS[256];

    const int tid = threadIdx.x;
    const int wave = tid >> 6, lane = tid & 63;
    const int ln = lane & 15, lq = lane >> 4;
    const int wm = wave >> 1, wn = wave & 1;   // wm: 32-row l band, wn: 64-col s half
    const int l0 = blockIdx.x * 128;
    const int bh = blockIdx.y;
    const int bq = bh >> 4, h = bh & 15;

    for (int u = tid; u < 1024; u += 512) {
        vvS[u] = vv[(size_t)bh * 1024 + u];
        aaS[u] = aa[(size_t)bh * 1024 + u];
        vaS[u] = va[(size_t)bh * 1024 + u];
    }
    if (tid < 128) {
        llS[tid] = ll[(size_t)bh * 512 + l0 + tid];
        mRow[tid] = -3.4e38f;
        sRow[tid] = 0.f;
    }
#pragma unroll
    for (int c = 0; c < 2; ++c) {          // stage Q once (128 x 64)
        const int row = wave * 16 + c * 8 + (lane >> 3);
        const int ch = (lane & 7) ^ (row & 7);
        gload_lds16(Qb + ((size_t)bh * 512 + l0 + row) * 64 + ch * 8,
                    (void*)(Qs + (wave * 16 + c * 8) * 64));
    }
    __syncthreads();

    f32x4 zero = {0.f, 0.f, 0.f, 0.f};

    // ---------------- pass 1: online max / expsum ----------------
    for (int st = 0; st < 8; ++st) {
        const int s0 = st * 128;
        __syncthreads();
#pragma unroll
        for (int c = 0; c < 2; ++c) {
            const int row = wave * 16 + c * 8 + (lane >> 3);
            const int ch = (lane & 7) ^ (row & 7);
            gload_lds16(K1b + ((size_t)bh * 1024 + s0 + row) * 64 + ch * 8,
                        (void*)(K1s + (wave * 16 + c * 8) * 64));
            gload_lds16(K2b + ((size_t)bh * 1024 + s0 + row) * 64 + ch * 8,
                        (void*)(K2s + (wave * 16 + c * 8) * 64));
        }
        __syncthreads();

        f32x4 lv[2][4], la[2][4];
#pragma unroll
        for (int i = 0; i < 2; ++i)
#pragma unroll
            for (int j = 0; j < 4; ++j) { lv[i][j] = zero; la[i][j] = zero; }
#pragma unroll
        for (int sub = 0; sub < 2; ++sub) {
            short8 qf[2], k1f[4], k2f[4];
#pragma unroll
            for (int i = 0; i < 2; ++i) {
                const int ml = wm * 32 + i * 16 + ln;
                qf[i] = *(const short8*)(Qs + ml * 64 + (((sub * 4 + lq) ^ (ml & 7)) * 8));
            }
#pragma unroll
            for (int j = 0; j < 4; ++j) {
                const int nl = wn * 64 + j * 16 + ln;
                k1f[j] = *(const short8*)(K1s + nl * 64 + (((sub * 4 + lq) ^ (nl & 7)) * 8));
                k2f[j] = *(const short8*)(K2s + nl * 64 + (((sub * 4 + lq) ^ (nl & 7)) * 8));
            }
#pragma unroll
            for (int i = 0; i < 2; ++i)
#pragma unroll
                for (int j = 0; j < 4; ++j) {
                    lv[i][j] = __builtin_amdgcn_mfma_f32_16x16x32_bf16(qf[i], k1f[j], lv[i][j], 0, 0, 0);
                    la[i][j] = __builtin_amdgcn_mfma_f32_16x16x32_bf16(qf[i], k2f[j], la[i][j], 0, 0, 0);
                }
        }
        // logits in-place into lv
#pragma unroll
        for (int i = 0; i < 2; ++i)
#pragma unroll
            for (int j = 0; j < 4; ++j) {
                const int s_loc = wn * 64 + j * 16 + ln;
                const float VV = vvS[s0 + s_loc], AA = aaS[s0 + s_loc], VA = vaS[s0 + s_loc];
#pragma unroll
                for (int r = 0; r < 4; ++r) {
                    const float LL = llS[wm * 32 + i * 16 + lq * 4 + r];
                    const float LV = lv[i][j][r], LA = la[i][j][r];
                    float det = LL * (VV * AA - VA * VA) - LV * (LV * AA - LA * VA) + LA * (LV * VA - LA * VV);
                    det = fmaxf(det, 1e-8f);
                    lv[i][j][r] = LV + LA - 1.5f * sqrtf(det);
                }
            }
        // row max (over j then across ln)
#pragma unroll
        for (int i = 0; i < 2; ++i)
#pragma unroll
            for (int r = 0; r < 4; ++r) {
                float m = fmaxf(fmaxf(lv[i][0][r], lv[i][1][r]), fmaxf(lv[i][2][r], lv[i][3][r]));
#pragma unroll
                for (int o = 1; o < 16; o <<= 1) m = fmaxf(m, __shfl_xor(m, o));
                if (ln == 0) redM[wn * 128 + wm * 32 + i * 16 + lq * 4 + r] = m;
            }
        __syncthreads();
        if (tid < 128) {
            const float mo = mRow[tid];
            const float mn = fmaxf(mo, fmaxf(redM[tid], redM[128 + tid]));
            sRow[tid] *= __expf(mo - mn);
            mRow[tid] = mn;
        }
        __syncthreads();
        // exp-sum per row
#pragma unroll
        for (int i = 0; i < 2; ++i)
#pragma unroll
            for (int r = 0; r < 4; ++r) {
                const float mr = mRow[wm * 32 + i * 16 + lq * 4 + r];
                float e = __expf(lv[i][0][r] - mr) + __expf(lv[i][1][r] - mr)
                        + __expf(lv[i][2][r] - mr) + __expf(lv[i][3][r] - mr);
#pragma unroll
                for (int o = 1; o < 16; o <<= 1) e += __shfl_xor(e, o);
                if (ln == 0) redS[wn * 128 + wm * 32 + i * 16 + lq * 4 + r] = e;
            }
        __syncthreads();
        if (tid < 128) sRow[tid] += redS[tid] + redS[128 + tid];
    }
    __syncthreads();
    if (tid < 128) sRow[tid] = 1.0f / sRow[tid];   // now holds inv-sum

    // ---------------- pass 2: p + attn write + PV ----------------
    f32x4 o1[4], o2[4];
#pragma unroll
    for (int j = 0; j < 4; ++j) { o1[j] = zero; o2[j] = zero; }

    for (int st = 0; st < 8; ++st) {
        const int s0 = st * 128;
        __syncthreads();
#pragma unroll
        for (int c = 0; c < 2; ++c) {
            const int row = wave * 16 + c * 8 + (lane >> 3);
            const int ch = (lane & 7) ^ (row & 7);
            gload_lds16(K1b + ((size_t)bh * 1024 + s0 + row) * 64 + ch * 8,
                        (void*)(K1s + (wave * 16 + c * 8) * 64));
            gload_lds16(K2b + ((size_t)bh * 1024 + s0 + row) * 64 + ch * 8,
                        (void*)(K2s + (wave * 16 + c * 8) * 64));
        }
#pragma unroll
        for (int c = 0; c < 2; ++c) {       // V tiles 64 d x 128 s
            const int dr = wave * 8 + c * 4 + (lane >> 4);
            const int ch = (lane & 15) ^ (dr & 7);
            gload_lds16(V1t + ((size_t)bh * 64 + dr) * 1024 + s0 + ch * 8,
                        (void*)(V1s + (wave * 8 + c * 4) * 128));
            gload_lds16(V2t + ((size_t)bh * 64 + dr) * 1024 + s0 + ch * 8,
                        (void*)(V2s + (wave * 8 + c * 4) * 128));
        }
        __syncthreads();

        f32x4 lv[2][4], la[2][4];
#pragma unroll
        for (int i = 0; i < 2; ++i)
#pragma unroll
            for (int j = 0; j < 4; ++j) { lv[i][j] = zero; la[i][j] = zero; }
#pragma unroll
        for (int sub = 0; sub < 2; ++sub) {
            short8 qf[2], k1f[4], k2f[4];
#pragma unroll
            for (int i = 0; i < 2; ++i) {
                const int ml = wm * 32 + i * 16 + ln;
                qf[i] = *(const short8*)(Qs + ml * 64 + (((sub * 4 + lq) ^ (ml & 7)) * 8));
            }
#pragma unroll
            for (int j = 0; j < 4; ++j) {
                const int nl = wn * 64 + j * 16 + ln;
                k1f[j] = *(const short8*)(K1s + nl * 64 + (((sub * 4 + lq) ^ (nl & 7)) * 8));
                k2f[j] = *(const short8*)(K2s + nl * 64 + (((sub * 4 + lq) ^ (nl & 7)) * 8));
            }
#pragma unroll
            for (int i = 0; i < 2; ++i)
#pragma unroll
                for (int j = 0; j < 4; ++j) {
                    lv[i][j] = __builtin_amdgcn_mfma_f32_16x16x32_bf16(qf[i], k1f[j], lv[i][j], 0, 0, 0);
                    la[i][j] = __builtin_amdgcn_mfma_f32_16x16x32_bf16(qf[i], k2f[j], la[i][j], 0, 0, 0);
                }
        }
        // p -> Ps (swizzled bf16)
#pragma unroll
        for (int i = 0; i < 2; ++i)
#pragma unroll
            for (int j = 0; j < 4; ++j) {
                const int s_loc = wn * 64 + j * 16 + ln;
                const float VV = vvS[s0 + s_loc], AA = aaS[s0 + s_loc], VA = vaS[s0 + s_loc];
#pragma unroll
                for (int r = 0; r < 4; ++r) {
                    const int l_loc = wm * 32 + i * 16 + lq * 4 + r;
                    const float LL = llS[l_loc];
                    const float LV = lv[i][j][r], LA = la[i][j][r];
                    float det = LL * (VV * AA - VA * VA) - LV * (LV * AA - LA * VA) + LA * (LV * VA - LA * VV);
                    det = fmaxf(det, 1e-8f);
                    const float lg = LV + LA - 1.5f * sqrtf(det);
                    const float p = __expf(lg - mRow[l_loc]) * sRow[l_loc];
                    Ps[l_loc * 128 + (((s_loc >> 3) ^ (l_loc & 7)) * 8) + (s_loc & 7)] = f2b(p);
                }
            }
        __syncthreads();
        // coalesced Ps -> attn global
#pragma unroll
        for (int it = 0; it < 4; ++it) {
            const int l = it * 32 + (tid >> 4);
            const int c = tid & 15;
            uint4 val = *(const uint4*)(Ps + l * 128 + ((c ^ (l & 7)) * 8));
            *(uint4*)( (void*)(attn + ((size_t)bh * 512 + l0 + l) * 1024 + s0 + c * 8) ) = val;
        }
        // PV: wave covers l rows wave*16..+15, all 64 d
#pragma unroll
        for (int kt = 0; kt < 4; ++kt) {
            const int lA = wave * 16 + ln;
            short8 pf = *(const short8*)(Ps + lA * 128 + (((kt * 4 + lq) ^ (lA & 7)) * 8));
#pragma unroll
            for (int j = 0; j < 4; ++j) {
                const int d = j * 16 + ln;
                short8 v1f = *(const short8*)(V1s + d * 128 + (((kt * 4 + lq) ^ (d & 7)) * 8));
                short8 v2f = *(const short8*)(V2s + d * 128 + (((kt * 4 + lq) ^ (d & 7)) * 8));
                o1[j] = __builtin_amdgcn_mfma_f32_16x16x32_bf16(pf, v1f, o1[j], 0, 0, 0);
                o2[j] = __builtin_amdgcn_mfma_f32_16x16x32_bf16(pf, v2f, o2[j], 0, 0, 0);
            }
        }
    }
    // gate epilogue -> tmpb
#pragma unroll
    for (int j = 0; j < 4; ++j)
#pragma unroll
        for (int r = 0; r < 4; ++r) {
            const int l = l0 + wave * 16 + lq * 4 + r;
            const int d = j * 16 + ln;
            const size_t addr = ((size_t)l * 4 + bq) * 1024 + h * 64 + d;
            const float v = 0.5f * (o1[j][r] * b2f(G1[addr]) + o2[j][r] * b2f(G2[addr]));
            tmpb[addr] = f2b(v);
        }
}

// ====== mean over heads -> avg_weights [B][L][S] (attn dense bf16) ======
__global__ __launch_bounds__(256)
void head_avg_kernel(const ushort_t* __restrict__ attn, float* __restrict__ outv)
{
    const int idx = blockIdx.x * 256 + threadIdx.x;  // B*L*S/8
    const int s8 = idx & 127;
    const int l = (idx >> 7) & 511;
    const int b = idx >> 16;
    float acc[8] = {};
#pragma unroll
    for (int h = 0; h < 16; ++h) {
        const ushort_t* p = attn + (((size_t)(b * 16 + h) * 512 + l)) * 1024 + s8 * 8;
        uint4 u = *(const uint4*)p;
        const uint_t uu[4] = {u.x, u.y, u.z, u.w};
#pragma unroll
        for (int q = 0; q < 4; ++q) {
            acc[2 * q]     += __uint_as_float((uu[q] & 0xffffu) << 16);
            acc[2 * q + 1] += __uint_as_float(uu[q] & 0xffff0000u);
        }
    }
    float* d = outv + (size_t)idx * 8;
    float4 o1 = {acc[0] * 0.0625f, acc[1] * 0.0625f, acc[2] * 0.0625f, acc[3] * 0.0625f};
    float4 o2 = {acc[4] * 0.0625f, acc[5] * 0.0625f, acc[6] * 0.0625f, acc[7] * 0.0625f};
    *(float4*)d = o1;
    *(float4*)(d + 4) = o2;
}

// ============ o-proj: 64x128 tiles, 256 blocks ============
__global__ __launch_bounds__(256, 2)
void gemm_o64(const ushort_t* __restrict__ A, const ushort_t* __restrict__ B,
              const float* __restrict__ bias, float* __restrict__ Y)
{
    __shared__ ushort_t As[64 * 64];
    __shared__ ushort_t Bs[128 * 64];
    const int tid = threadIdx.x;
    const int wave = tid >> 6, lane = tid & 63;
    const int ln = lane & 15, lq = lane >> 4;
    const int row0 = blockIdx.y * 64, col0 = blockIdx.x * 128;
    const int wm = wave & 1, wn = wave >> 1;
    const int cswz = (lane & 7) ^ ((lane >> 3) & 7);
    const int mrl = lane >> 3;

    f32x4 zero = {0.f, 0.f, 0.f, 0.f};
    f32x4 acc[2][4];
#pragma unroll
    for (int i = 0; i < 2; ++i)
#pragma unroll
        for (int j = 0; j < 4; ++j) acc[i][j] = zero;

    for (int kk = 0; kk < 1024; kk += 64) {
        __syncthreads();
#pragma unroll
        for (int j = 0; j < 2; ++j) {
            const int mr = (wave * 2 + j) * 8 + mrl;
            gload_lds16(A + (size_t)(row0 + mr) * 1024 + kk + cswz * 8,
                        (void*)(As + (wave * 2 + j) * 512));
        }
#pragma unroll
        for (int j = 0; j < 4; ++j) {
            const int mr = (wave * 4 + j) * 8 + mrl;
            gload_lds16(B + (size_t)(col0 + mr) * 1024 + kk + cswz * 8,
                        (void*)(Bs + (wave * 4 + j) * 512));
        }
        __syncthreads();
#pragma unroll
        for (int sub = 0; sub < 2; ++sub) {
            short8 af[2], bfv[4];
#pragma unroll
            for (int i = 0; i < 2; ++i) {
                const int ml = wm * 32 + i * 16 + ln;
                af[i] = *(const short8*)(As + ml * 64 + (((sub * 4 + lq) ^ (ml & 7)) * 8));
            }
#pragma unroll
            for (int j = 0; j < 4; ++j) {
                const int nl = wn * 64 + j * 16 + ln;
                bfv[j] = *(const short8*)(Bs + nl * 64 + (((sub * 4 + lq) ^ (nl & 7)) * 8));
            }
#pragma unroll
            for (int i = 0; i < 2; ++i)
#pragma unroll
                for (int j = 0; j < 4; ++j)
                    acc[i][j] = __builtin_amdgcn_mfma_f32_16x16x32_bf16(af[i], bfv[j], acc[i][j], 0, 0, 0);
        }
    }

#pragma unroll
    for (int i = 0; i < 2; ++i) {
#pragma unroll
        for (int r = 0; r < 4; ++r) {
            const int row = row0 + wm * 32 + i * 16 + lq * 4 + r;
#pragma unroll
            for (int j = 0; j < 4; ++j) {
                const int col = col0 + wn * 64 + j * 16 + ln;
                Y[(size_t)row * 1024 + col] = acc[i][j][r] + bias[col];
            }
        }
    }
}

// ============================ launch ============================
extern "C" void kernel_launch(void* const* d_in, const int* in_sizes, int n_in,
                              void* d_out, int out_size, void* d_ws, size_t ws_size,
                              hipStream_t stream)
{
    const float* query = (const float*)d_in[0];
    const float* mod1  = (const float*)d_in[1];
    const float* mod2  = (const float*)d_in[2];
    const float* q_w  = (const float*)d_in[3];  const float* q_b  = (const float*)d_in[4];
    const float* k1_w = (const float*)d_in[5];  const float* k1_b = (const float*)d_in[6];
    const float* k2_w = (const float*)d_in[7];  const float* k2_b = (const float*)d_in[8];
    const float* v1_w = (const float*)d_in[9];  const float* v1_b = (const float*)d_in[10];
    const float* v2_w = (const float*)d_in[11]; const float* v2_b = (const float*)d_in[12];
    const float* g1_w = (const float*)d_in[13]; const float* g1_b = (const float*)d_in[14];
    const float* g2_w = (const float*)d_in[15]; const float* g2_b = (const float*)d_in[16];
    const float* o_w  = (const float*)d_in[17]; const float* o_b  = (const float*)d_in[18];
    float* out = (float*)d_out;

    const size_t MB = 1u << 20;
    char* w = (char*)d_ws;
    // persistent region (0..78 MB)
    ushort_t* Wqg  = (ushort_t*)(w + 0 * MB);    // 6 MB [q|g1|g2]^T
    ushort_t* Wkv1 = (ushort_t*)(w + 6 * MB);    // 4 MB [k1|v1]^T
    ushort_t* Wkv2 = (ushort_t*)(w + 10 * MB);   // 4 MB [k2|v2]^T
    ushort_t* Wo   = (ushort_t*)(w + 14 * MB);   // 2 MB
    ushort_t* Wk1l = (ushort_t*)(w + 16 * MB);   // 2 MB
    ushort_t* Wk2l = (ushort_t*)(w + 18 * MB);   // 2 MB
    ushort_t* qx   = (ushort_t*)(w + 20 * MB);   // 4 MB; dead after mega-GEMM
    ushort_t* tmpb = qx;                         // reuse for gated PV output
    ushort_t* Qb   = (ushort_t*)(w + 24 * MB);   // 4 MB
    ushort_t* K1b  = (ushort_t*)(w + 28 * MB);   // 8 MB
    ushort_t* K2b  = (ushort_t*)(w + 36 * MB);   // 8 MB
    ushort_t* V1t  = (ushort_t*)(w + 44 * MB);   // 8 MB
    ushort_t* V2t  = (ushort_t*)(w + 52 * MB);   // 8 MB
    ushort_t* G1b  = (ushort_t*)(w + 60 * MB);   // 4 MB bf16 gates
    ushort_t* G2b  = (ushort_t*)(w + 64 * MB);   // 4 MB
    float* ll = (float*)(w + 68 * MB);                   // 128 KB
    float* vv = (float*)(w + 68 * MB + 256 * 1024);      // 256 KB
    float* aa = (float*)(w + 68 * MB + 512 * 1024);
    float* va = (float*)(w + 68 * MB + 768 * 1024);
    // transient region 78..158 MB (overlays, all dead before flash):
    ushort_t* attn = (ushort_t*)(w + 78 * MB);   // 64 MB dense bf16 [bh][512][1024]
    ushort_t* m1h = (ushort_t*)(w + 78 * MB);    // 8 MB  (dead after mega-GEMM)
    ushort_t* m2h = (ushort_t*)(w + 86 * MB);    // 8 MB
    ushort_t* m1l = (ushort_t*)(w + 94 * MB);    // 8 MB
    ushort_t* m2l = (ushort_t*)(w + 102 * MB);   // 8 MB
    float* K1f = (float*)(w + 110 * MB);         // 16 MB (dead after prep)
    float* K2f = (float*)(w + 126 * MB);         // 16 MB
    ushort_t* V1b = (ushort_t*)(w + 142 * MB);   // 8 MB (dead after prep)
    ushort_t* V2b = (ushort_t*)(w + 150 * MB);   // 8 MB

    // 1) fused casts
    CastArgs ca;
    ca.q = query; ca.m1 = mod1; ca.m2 = mod2;
    ca.qx = qx; ca.m1h = m1h; ca.m1l = m1l; ca.m2h = m2h; ca.m2l = m2l;
    const float* srcs[8] = {q_w, g1_w, g2_w, k1_w, v1_w, k2_w, v2_w, o_w};
    ushort_t* his[8] = {Wqg, Wqg + (size_t)1024 * 1024, Wqg + (size_t)2048 * 1024,
                        Wkv1, Wkv1 + (size_t)1024 * 1024, Wkv2, Wkv2 + (size_t)1024 * 1024, Wo};
    ushort_t* los[8] = {nullptr, nullptr, nullptr, Wk1l, nullptr, Wk2l, nullptr, nullptr};
    for (int i = 0; i < 8; ++i) { ca.wsrc[i] = srcs[i]; ca.whi[i] = his[i]; ca.wlo[i] = los[i]; }
    casts_kernel<<<7168, 256, 0, stream>>>(ca);

    // 2) all projections, one balanced launch
    MegaArgs ma;
    ma.qx = qx; ma.m1h = m1h; ma.m1l = m1l; ma.m2h = m2h; ma.m2l = m2l;
    ma.Wqg = Wqg; ma.Wkv1 = Wkv1; ma.Wkv2 = Wkv2; ma.Wk1l = Wk1l; ma.Wk2l = Wk2l;
    ma.q_b = q_b; ma.k1_b = k1_b; ma.k2_b = k2_b; ma.v1_b = v1_b; ma.v2_b = v2_b;
    ma.g1_b = g1_b; ma.g2_b = g2_b;
    ma.K1f = K1f; ma.K2f = K2f; ma.V1b = V1b; ma.V2b = V2b;
    ma.Qb = Qb; ma.G1b = G1b; ma.G2b = G2b;
    mega_gemm<<<1408, 256, 0, stream>>>(ma);

    // 3) fused prep (K norms+cast, Q norms, V transpose)
    prep_kernel<<<26624, 256, 0, stream>>>(K1f, K2f, K1b, K2b, vv, aa, va,
                                           Qb, ll, V1b, V2b, V1t, V2t);

    // 4) flash attention (scores+softmax+PV+gates fused; attn stored for avg)
    flash_attn<<<dim3(4, 64), 512, 0, stream>>>(Qb, K1b, K2b, V1t, V2t,
                                                ll, vv, aa, va, G1b, G2b, attn, tmpb);

    // 5-6) head average + output projection
    head_avg_kernel<<<1024, 256, 0, stream>>>(attn, out + (size_t)LQ * NB * EDIM);
    gemm_o64<<<dim3(8, 32), 256, 0, stream>>>(tmpb, Wo, o_b, out);
}

// Round 8
// 397.552 us; speedup vs baseline: 1.1168x; 1.1168x over previous
//
#include <hip/hip_runtime.h>
#include <cstddef>
#include <cstdint>

typedef unsigned short ushort_t;
typedef unsigned int uint_t;
typedef __attribute__((ext_vector_type(8))) short short8;
typedef __attribute__((ext_vector_type(4))) float f32x4;

#define EDIM 1024
#define NHEAD 16
#define HDIM 64
#define NB 4
#define LQ 512
#define SK 1024
#define BHD 64

__device__ __forceinline__ ushort_t f2b(float f) {
    uint_t u = __float_as_uint(f);
    return (ushort_t)((u + 0x7fffu + ((u >> 16) & 1u)) >> 16);
}
__device__ __forceinline__ float b2f(ushort_t b) {
    return __uint_as_float(((uint_t)b) << 16);
}

__device__ __forceinline__ void gload_lds16(const void* g, void* l) {
    __builtin_amdgcn_global_load_lds((const __attribute__((address_space(1))) void*)g,
                                     (__attribute__((address_space(3))) void*)l, 16, 0, 0);
}

// ============ mega projection GEMM: all 5 jobs in one balanced launch ======
struct MegaArgs {
    const ushort_t *qx, *m1h, *m1l, *m2h, *m2l;
    const ushort_t *Wqg, *Wkv1, *Wkv2, *Wk1l, *Wk2l;
    const float *q_b, *k1_b, *k2_b, *v1_b, *v2_b, *g1_b, *g2_b;
    float *K1f, *K2f;
    ushort_t *V1b, *V2b, *Qb, *G1b, *G2b;
};

__global__ __launch_bounds__(256, 2)
void mega_gemm(MegaArgs a)
{
    __shared__ ushort_t As[128 * 64];
    __shared__ ushort_t Bs[128 * 64];
    const int tid = threadIdx.x;
    const int wave = tid >> 6, lane = tid & 63;
    const int ln = lane & 15, lq = lane >> 4;
    const int wm = wave & 1, wn = wave >> 1;
    const int cswz = (lane & 7) ^ ((lane >> 3) & 7);
    const int mrl = lane >> 3;

    const int id = blockIdx.x;
    const ushort_t *A, *Al, *B, *Bl;
    const float* bias;
    int npass, row0, col0, kind;
    if (id < 512) {  // K split-precision, long blocks first
        kind = id >> 8;
        const int t = id & 255;
        col0 = (t & 7) * 128; row0 = (t >> 3) * 128; npass = 3;
        A = kind ? a.m2h : a.m1h;  Al = kind ? a.m2l : a.m1l;
        B = kind ? a.Wkv2 : a.Wkv1; Bl = kind ? a.Wk2l : a.Wk1l;
        bias = kind ? a.k2_b : a.k1_b;
    } else if (id < 1024) {  // V
        int t = id - 512; kind = 2 + (t >> 8); t &= 255;
        col0 = (t & 7) * 128; row0 = (t >> 3) * 128; npass = 1;
        A = (kind == 2) ? a.m1h : a.m2h; Al = A;
        B = ((kind == 2) ? a.Wkv1 : a.Wkv2) + (size_t)1024 * 1024; Bl = B;
        bias = (kind == 2) ? a.v1_b : a.v2_b;
    } else {  // QG
        const int t = id - 1024; kind = 4;
        const int c = t % 24, rr = t / 24;
        col0 = c * 128; row0 = rr * 128; npass = 1;
        A = a.qx; Al = A; B = a.Wqg; Bl = B;
        const int seg = c >> 3;
        bias = (seg == 0) ? a.q_b : ((seg == 1) ? a.g1_b : a.g2_b);
    }

    f32x4 zero = {0.f, 0.f, 0.f, 0.f};
    f32x4 acc[4][4];
#pragma unroll
    for (int i = 0; i < 4; ++i)
#pragma unroll
        for (int j = 0; j < 4; ++j) acc[i][j] = zero;

    for (int pp = 0; pp < npass; ++pp) {
        const ushort_t* Ab = (pp == 2) ? Al : A;   // AhBh + AhBl + AlBh
        const ushort_t* Bb = (pp == 1) ? Bl : B;
        for (int kk = 0; kk < 1024; kk += 64) {
            __syncthreads();
#pragma unroll
            for (int j = 0; j < 4; ++j) {
                const int mr = (wave * 4 + j) * 8 + mrl;
                gload_lds16(Ab + (size_t)(row0 + mr) * 1024 + kk + cswz * 8,
                            (void*)(As + (wave * 4 + j) * 512));
                gload_lds16(Bb + (size_t)(col0 + mr) * 1024 + kk + cswz * 8,
                            (void*)(Bs + (wave * 4 + j) * 512));
            }
            __syncthreads();
#pragma unroll
            for (int sub = 0; sub < 2; ++sub) {
                short8 af[4], bfv[4];
#pragma unroll
                for (int i = 0; i < 4; ++i) {
                    const int ml = wm * 64 + i * 16 + ln;
                    af[i] = *(const short8*)(As + ml * 64 + (((sub * 4 + lq) ^ (ml & 7)) * 8));
                    const int nl = wn * 64 + i * 16 + ln;
                    bfv[i] = *(const short8*)(Bs + nl * 64 + (((sub * 4 + lq) ^ (nl & 7)) * 8));
                }
#pragma unroll
                for (int i = 0; i < 4; ++i)
#pragma unroll
                    for (int j = 0; j < 4; ++j)
                        acc[i][j] = __builtin_amdgcn_mfma_f32_16x16x32_bf16(af[i], bfv[j], acc[i][j], 0, 0, 0);
            }
        }
    }

#pragma unroll
    for (int i = 0; i < 4; ++i) {
#pragma unroll
        for (int r = 0; r < 4; ++r) {
            const int row = row0 + wm * 64 + i * 16 + lq * 4 + r;
#pragma unroll
            for (int j = 0; j < 4; ++j) {
                const int col = col0 + wn * 64 + j * 16 + ln;
                const int lc = col & 1023;
                float v = acc[i][j][r] + bias[lc];
                if (kind <= 1) {            // K fp32 head-split (S=1024)
                    const int s = row >> 2, b = row & 3, h = lc >> 6, d = lc & 63;
                    float* Y = kind ? a.K2f : a.K1f;
                    Y[(((size_t)(b * 16 + h)) * 1024 + s) * 64 + d] = v;
                } else if (kind <= 3) {     // V bf16 head-split
                    const int s = row >> 2, b = row & 3, h = lc >> 6, d = lc & 63;
                    ushort_t* Y = (kind == 2) ? a.V1b : a.V2b;
                    Y[(((size_t)(b * 16 + h)) * 1024 + s) * 64 + d] = f2b(v);
                } else {
                    const int seg = col >> 10;
                    if (seg == 0) {         // Q bf16 head-split (L=512), *scale
                        v *= 0.125f;
                        const int s = row >> 2, b = row & 3, h = lc >> 6, d = lc & 63;
                        a.Qb[(((size_t)(b * 16 + h)) * 512 + s) * 64 + d] = f2b(v);
                    } else {                // gates bf16 sigmoid flat
                        v = 1.0f / (1.0f + __expf(-v));
                        ushort_t* Y = (seg == 1) ? a.G1b : a.G2b;
                        Y[(size_t)row * 1024 + lc] = f2b(v);
                    }
                }
            }
        }
    }
}

// =============== fused input/weight casts (one launch) ===============
struct CastArgs {
    const float* q; const float* m1; const float* m2;
    ushort_t* qx; ushort_t* m1h; ushort_t* m1l; ushort_t* m2h; ushort_t* m2l;
    const float* wsrc[8];
    ushort_t* whi[8];
    ushort_t* wlo[8];
};

__global__ __launch_bounds__(256)
void casts_kernel(CastArgs a)
{
    __shared__ float T[64][65];
    const int id = blockIdx.x;
    const int tid = threadIdx.x;
    if (id < 1024) {                       // query cast
        const size_t i = ((size_t)id * 256 + tid) * 8;
        float4 x = *(const float4*)(a.q + i);
        float4 y = *(const float4*)(a.q + i + 4);
        ushort_t o[8] = {f2b(x.x), f2b(x.y), f2b(x.z), f2b(x.w), f2b(y.x), f2b(y.y), f2b(y.z), f2b(y.w)};
        *(uint4*)( (void*)(a.qx + i) ) = *(const uint4*)o;
    } else if (id < 5120) {                // mod hi/lo split casts
        const int t = id - 1024;
        const int which = t >> 11;
        const float* x = which ? a.m2 : a.m1;
        ushort_t* yh = which ? a.m2h : a.m1h;
        ushort_t* yl = which ? a.m2l : a.m1l;
        const size_t i = ((size_t)(t & 2047) * 256 + tid) * 8;
        float v[8];
        *(float4*)v = *(const float4*)(x + i);
        *(float4*)(v + 4) = *(const float4*)(x + i + 4);
        ushort_t oh[8], ol[8];
#pragma unroll
        for (int k = 0; k < 8; ++k) {
            oh[k] = f2b(v[k]);
            ol[k] = f2b(v[k] - b2f(oh[k]));
        }
        *(uint4*)( (void*)(yh + i) ) = *(const uint4*)oh;
        *(uint4*)( (void*)(yl + i) ) = *(const uint4*)ol;
    } else {                               // weight transpose+cast
        const int t = id - 5120;
        const int z = t >> 8, x = t & 15, y = (t >> 4) & 15;
        const float* W = a.wsrc[z];
        ushort_t* Th = a.whi[z];
        ushort_t* Tl = a.wlo[z];
        const int k0 = x * 64, n0 = y * 64;
        const int r = tid >> 2, cg = (tid & 3) * 16;
#pragma unroll
        for (int u = 0; u < 4; ++u) {
            float4 v = *(const float4*)(W + (size_t)(k0 + r) * 1024 + n0 + cg + u * 4);
            T[r][cg + u * 4 + 0] = v.x; T[r][cg + u * 4 + 1] = v.y;
            T[r][cg + u * 4 + 2] = v.z; T[r][cg + u * 4 + 3] = v.w;
        }
        __syncthreads();
        ushort_t oh[16], ol[16];
#pragma unroll
        for (int u = 0; u < 16; ++u) {
            float v = T[cg + u][r];
            oh[u] = f2b(v);
            ol[u] = f2b(v - b2f(oh[u]));
        }
        ushort_t* dh = Th + (size_t)(n0 + r) * 1024 + k0 + cg;
        *(uint4*)( (void*)dh ) = *(const uint4*)oh;
        *(uint4*)( (void*)(dh + 8) ) = *(const uint4*)(oh + 8);
        if (Tl) {
            ushort_t* dl = Tl + (size_t)(n0 + r) * 1024 + k0 + cg;
            *(uint4*)( (void*)dl ) = *(const uint4*)ol;
            *(uint4*)( (void*)(dl + 8) ) = *(const uint4*)(ol + 8);
        }
    }
}

// ====== fused prep: K norms+cast, Q norms, V transpose (one launch) ======
__global__ __launch_bounds__(256)
void prep_kernel(const float* __restrict__ K1f, const float* __restrict__ K2f,
                 ushort_t* __restrict__ K1b, ushort_t* __restrict__ K2b,
                 float* __restrict__ vv, float* __restrict__ aa, float* __restrict__ va,
                 const ushort_t* __restrict__ Qb, float* __restrict__ ll,
                 const ushort_t* __restrict__ V1b, const ushort_t* __restrict__ V2b,
                 ushort_t* __restrict__ V1t, ushort_t* __restrict__ V2t)
{
    __shared__ float T[64][65];
    const int id = blockIdx.x;
    const int tid = threadIdx.x;
    const int wave = tid >> 6, lane = tid & 63;
    if (id < 16384) {                      // K norms (fp32) + bf16 cast
        const int row = id * 4 + wave;
        const float x1 = K1f[(size_t)row * 64 + lane];
        const float x2 = K2f[(size_t)row * 64 + lane];
        K1b[(size_t)row * 64 + lane] = f2b(x1);
        K2b[(size_t)row * 64 + lane] = f2b(x2);
        float s1 = x1 * x1, s2 = x2 * x2, s3 = x1 * x2;
#pragma unroll
        for (int o = 1; o < 64; o <<= 1) {
            s1 += __shfl_xor(s1, o);
            s2 += __shfl_xor(s2, o);
            s3 += __shfl_xor(s3, o);
        }
        if (lane == 0) { vv[row] = s1; aa[row] = s2; va[row] = s3; }
    } else if (id < 24576) {               // Q norms
        const int row = (id - 16384) * 4 + wave;
        const float x = b2f(Qb[(size_t)row * 64 + lane]);
        float s = x * x;
#pragma unroll
        for (int o = 1; o < 64; o <<= 1) s += __shfl_xor(s, o);
        if (lane == 0) ll[row] = s;
    } else {                               // V transpose
        const int t = id - 24576;
        const int z = t >> 10, bh = (t >> 4) & 63, s0 = (t & 15) * 64;
        const ushort_t* S = z ? V2b : V1b;
        ushort_t* D = z ? V2t : V1t;
        const int r = tid >> 2, cg = (tid & 3) * 16;
        ushort_t buf[16];
        const ushort_t* sp = S + ((size_t)bh * 1024 + s0 + r) * 64 + cg;
        *(uint4*)buf = *(const uint4*)sp;
        *(uint4*)(buf + 8) = *(const uint4*)(sp + 8);
#pragma unroll
        for (int u = 0; u < 16; ++u) T[r][cg + u] = b2f(buf[u]);
        __syncthreads();
        ushort_t o[16];
#pragma unroll
        for (int u = 0; u < 16; ++u) o[u] = f2b(T[cg + u][r]);
        ushort_t* d = D + ((size_t)bh * 64 + r) * 1024 + s0 + cg;
        *(uint4*)( (void*)d ) = *(const uint4*)o;
        *(uint4*)( (void*)(d + 8) ) = *(const uint4*)(o + 8);
    }
}

// ======== single-pass flash attention with a-priori softmax bound =========
// logit <= M_row = sqrt(LL)*(max_s sqrt(VV) + max_s sqrt(AA))  (Cauchy-Schwarz,
// gram term <= 0). e = exp(l - M_row) stored unnormalized (bf16) to attn;
// invS = 1/sum(e) stored per row; PV accumulates unnormalized, epilogue
// normalizes with gates. Ps overlays the K LDS region (dead after QK).
__global__ __launch_bounds__(512, 1)
void flash_attn(const ushort_t* __restrict__ Qb, const ushort_t* __restrict__ K1b,
                const ushort_t* __restrict__ K2b, const ushort_t* __restrict__ V1t,
                const ushort_t* __restrict__ V2t, const float* __restrict__ ll,
                const float* __restrict__ vv, const float* __restrict__ aa,
                const float* __restrict__ va, const ushort_t* __restrict__ G1,
                const ushort_t* __restrict__ G2, ushort_t* __restrict__ attn,
                float* __restrict__ invS, ushort_t* __restrict__ tmpb)
{
    __shared__ ushort_t Qs[128 * 64];
    __shared__ ushort_t KPs[2 * 128 * 64];   // K1s | K2s ; Ps (128x128) overlays
    __shared__ ushort_t V1s[64 * 128];
    __shared__ ushort_t V2s[64 * 128];
    __shared__ float vvS[1024], aaS[1024], vaS[1024];
    __shared__ float llS[128], MrS[128];
    __shared__ float red[256];

    const int tid = threadIdx.x;
    const int wave = tid >> 6, lane = tid & 63;
    const int ln = lane & 15, lq = lane >> 4;
    const int wm = wave >> 1, wn = wave & 1;
    const int l0 = blockIdx.x * 128;
    const int bh = blockIdx.y;
    const int bq = bh >> 4, h = bh & 15;
    ushort_t* K1s = KPs;
    ushort_t* K2s = KPs + 128 * 64;
    ushort_t* Ps  = KPs;

    for (int u = tid; u < 1024; u += 512) {
        vvS[u] = vv[(size_t)bh * 1024 + u];
        aaS[u] = aa[(size_t)bh * 1024 + u];
        vaS[u] = va[(size_t)bh * 1024 + u];
    }
    if (tid < 128) llS[tid] = ll[(size_t)bh * 512 + l0 + tid];
#pragma unroll
    for (int c = 0; c < 2; ++c) {          // stage Q once (128 x 64)
        const int row = wave * 16 + c * 8 + (lane >> 3);
        const int ch = (lane & 7) ^ (row & 7);
        gload_lds16(Qb + ((size_t)bh * 512 + l0 + row) * 64 + ch * 8,
                    (void*)(Qs + (wave * 16 + c * 8) * 64));
    }
    __syncthreads();

    // softmax bound: M_row = sqrt(LL)*(sqrt(max VV) + sqrt(max AA))
    {
        float mv = fmaxf(vvS[tid], vvS[tid + 512]);
        float ma = fmaxf(aaS[tid], aaS[tid + 512]);
#pragma unroll
        for (int o = 1; o < 64; o <<= 1) {
            mv = fmaxf(mv, __shfl_xor(mv, o));
            ma = fmaxf(ma, __shfl_xor(ma, o));
        }
        if (lane == 0) { red[wave] = mv; red[8 + wave] = ma; }
    }
    __syncthreads();
    if (tid < 128) {
        float mv = fmaxf(fmaxf(fmaxf(red[0], red[1]), fmaxf(red[2], red[3])),
                         fmaxf(fmaxf(red[4], red[5]), fmaxf(red[6], red[7])));
        float ma = fmaxf(fmaxf(fmaxf(red[8], red[9]), fmaxf(red[10], red[11])),
                         fmaxf(fmaxf(red[12], red[13]), fmaxf(red[14], red[15])));
        MrS[tid] = sqrtf(llS[tid]) * (sqrtf(mv) + sqrtf(ma));
    }
    __syncthreads();

    // per-thread row constants
    float LLr[2][4], Mrr[2][4], esum[2][4];
#pragma unroll
    for (int i = 0; i < 2; ++i)
#pragma unroll
        for (int r = 0; r < 4; ++r) {
            const int row = wm * 32 + i * 16 + lq * 4 + r;
            LLr[i][r] = llS[row];
            Mrr[i][r] = MrS[row];
            esum[i][r] = 0.f;
        }

    f32x4 zero = {0.f, 0.f, 0.f, 0.f};
    f32x4 o1[4], o2[4];
#pragma unroll
    for (int j = 0; j < 4; ++j) { o1[j] = zero; o2[j] = zero; }

    for (int st = 0; st < 8; ++st) {
        const int s0 = st * 128;
        __syncthreads();                   // prior Ps/V readers done
#pragma unroll
        for (int c = 0; c < 2; ++c) {
            const int row = wave * 16 + c * 8 + (lane >> 3);
            const int ch = (lane & 7) ^ (row & 7);
            gload_lds16(K1b + ((size_t)bh * 1024 + s0 + row) * 64 + ch * 8,
                        (void*)(K1s + (wave * 16 + c * 8) * 64));
            gload_lds16(K2b + ((size_t)bh * 1024 + s0 + row) * 64 + ch * 8,
                        (void*)(K2s + (wave * 16 + c * 8) * 64));
        }
#pragma unroll
        for (int c = 0; c < 2; ++c) {       // V tiles 64 d x 128 s
            const int dr = wave * 8 + c * 4 + (lane >> 4);
            const int ch = (lane & 15) ^ (dr & 7);
            gload_lds16(V1t + ((size_t)bh * 64 + dr) * 1024 + s0 + ch * 8,
                        (void*)(V1s + (wave * 8 + c * 4) * 128));
            gload_lds16(V2t + ((size_t)bh * 64 + dr) * 1024 + s0 + ch * 8,
                        (void*)(V2s + (wave * 8 + c * 4) * 128));
        }
        __syncthreads();

        f32x4 lv[2][4], la[2][4];
#pragma unroll
        for (int i = 0; i < 2; ++i)
#pragma unroll
            for (int j = 0; j < 4; ++j) { lv[i][j] = zero; la[i][j] = zero; }
#pragma unroll
        for (int sub = 0; sub < 2; ++sub) {
            short8 qf[2], k1f[4], k2f[4];
#pragma unroll
            for (int i = 0; i < 2; ++i) {
                const int ml = wm * 32 + i * 16 + ln;
                qf[i] = *(const short8*)(Qs + ml * 64 + (((sub * 4 + lq) ^ (ml & 7)) * 8));
            }
#pragma unroll
            for (int j = 0; j < 4; ++j) {
                const int nl = wn * 64 + j * 16 + ln;
                k1f[j] = *(const short8*)(K1s + nl * 64 + (((sub * 4 + lq) ^ (nl & 7)) * 8));
                k2f[j] = *(const short8*)(K2s + nl * 64 + (((sub * 4 + lq) ^ (nl & 7)) * 8));
            }
#pragma unroll
            for (int i = 0; i < 2; ++i)
#pragma unroll
                for (int j = 0; j < 4; ++j) {
                    lv[i][j] = __builtin_amdgcn_mfma_f32_16x16x32_bf16(qf[i], k1f[j], lv[i][j], 0, 0, 0);
                    la[i][j] = __builtin_amdgcn_mfma_f32_16x16x32_bf16(qf[i], k2f[j], la[i][j], 0, 0, 0);
                }
        }
        // logits -> unnormalized e (in-place into lv), accumulate esum
#pragma unroll
        for (int j = 0; j < 4; ++j) {
            const int s_loc = wn * 64 + j * 16 + ln;
            const float VV = vvS[s0 + s_loc], AA = aaS[s0 + s_loc], VA = vaS[s0 + s_loc];
            const float P1 = VV * AA - VA * VA;
#pragma unroll
            for (int i = 0; i < 2; ++i)
#pragma unroll
                for (int r = 0; r < 4; ++r) {
                    const float LV = lv[i][j][r], LA = la[i][j][r];
                    float det = LLr[i][r] * P1 - (LV * LV) * AA
                              + 2.f * VA * (LV * LA) - (LA * LA) * VV;
                    det = fmaxf(det, 1e-8f);
                    const float lg = LV + LA - 1.5f * sqrtf(det);
                    const float e = __expf(lg - Mrr[i][r]);
                    esum[i][r] += e;
                    lv[i][j][r] = e;
                }
        }
        __syncthreads();                   // all QK reads of K region done
        // write Ps (bf16, swizzled) into K region
#pragma unroll
        for (int i = 0; i < 2; ++i)
#pragma unroll
            for (int j = 0; j < 4; ++j) {
                const int s_loc = wn * 64 + j * 16 + ln;
#pragma unroll
                for (int r = 0; r < 4; ++r) {
                    const int l_loc = wm * 32 + i * 16 + lq * 4 + r;
                    Ps[l_loc * 128 + (((s_loc >> 3) ^ (l_loc & 7)) * 8) + (s_loc & 7)] = f2b(lv[i][j][r]);
                }
            }
        __syncthreads();
        // coalesced Ps -> attn global (unnormalized)
#pragma unroll
        for (int it = 0; it < 4; ++it) {
            const int l = it * 32 + (tid >> 4);
            const int c = tid & 15;
            uint4 val = *(const uint4*)(Ps + l * 128 + ((c ^ (l & 7)) * 8));
            *(uint4*)( (void*)(attn + ((size_t)bh * 512 + l0 + l) * 1024 + s0 + c * 8) ) = val;
        }
        // PV: wave covers l rows wave*16..+15, all 64 d
#pragma unroll
        for (int kt = 0; kt < 4; ++kt) {
            const int lA = wave * 16 + ln;
            short8 pf = *(const short8*)(Ps + lA * 128 + (((kt * 4 + lq) ^ (lA & 7)) * 8));
#pragma unroll
            for (int j = 0; j < 4; ++j) {
                const int d = j * 16 + ln;
                short8 v1f = *(const short8*)(V1s + d * 128 + (((kt * 4 + lq) ^ (d & 7)) * 8));
                short8 v2f = *(const short8*)(V2s + d * 128 + (((kt * 4 + lq) ^ (d & 7)) * 8));
                o1[j] = __builtin_amdgcn_mfma_f32_16x16x32_bf16(pf, v1f, o1[j], 0, 0, 0);
                o2[j] = __builtin_amdgcn_mfma_f32_16x16x32_bf16(pf, v2f, o2[j], 0, 0, 0);
            }
        }
    }

    // reduce esum: over ln lanes, then across wn waves via LDS
#pragma unroll
    for (int i = 0; i < 2; ++i)
#pragma unroll
        for (int r = 0; r < 4; ++r) {
            float e = esum[i][r];
            e += __shfl_xor(e, 1); e += __shfl_xor(e, 2);
            e += __shfl_xor(e, 4); e += __shfl_xor(e, 8);
            if (ln == 0) red[wn * 128 + wm * 32 + i * 16 + lq * 4 + r] = e;
        }
    __syncthreads();
    if (tid < 128) {
        const float inv = 1.0f / (red[tid] + red[128 + tid]);
        llS[tid] = inv;                      // reuse as per-row inv
        invS[(size_t)bh * 512 + l0 + tid] = inv;
    }
    __syncthreads();

    // gate + normalize epilogue -> tmpb
#pragma unroll
    for (int j = 0; j < 4; ++j)
#pragma unroll
        for (int r = 0; r < 4; ++r) {
            const int l_loc = wave * 16 + lq * 4 + r;
            const float inv = llS[l_loc];
            const int l = l0 + l_loc;
            const int d = j * 16 + ln;
            const size_t addr = ((size_t)l * 4 + bq) * 1024 + h * 64 + d;
            const float v = 0.5f * inv * (o1[j][r] * b2f(G1[addr]) + o2[j][r] * b2f(G2[addr]));
            tmpb[addr] = f2b(v);
        }
}

// ====== mean over heads with deferred normalization ======
__global__ __launch_bounds__(256)
void head_avg_kernel(const ushort_t* __restrict__ attn, const float* __restrict__ invS,
                     float* __restrict__ outv)
{
    const int idx = blockIdx.x * 256 + threadIdx.x;  // B*L*S/8
    const int s8 = idx & 127;
    const int l = (idx >> 7) & 511;
    const int b = idx >> 16;
    float acc[8] = {};
#pragma unroll
    for (int h = 0; h < 16; ++h) {
        const float inv = invS[(size_t)(b * 16 + h) * 512 + l];
        const ushort_t* p = attn + (((size_t)(b * 16 + h) * 512 + l)) * 1024 + s8 * 8;
        uint4 u = *(const uint4*)p;
        const uint_t uu[4] = {u.x, u.y, u.z, u.w};
#pragma unroll
        for (int q = 0; q < 4; ++q) {
            acc[2 * q]     += __uint_as_float((uu[q] & 0xffffu) << 16) * inv;
            acc[2 * q + 1] += __uint_as_float(uu[q] & 0xffff0000u) * inv;
        }
    }
    float* d = outv + (size_t)idx * 8;
    float4 o1 = {acc[0] * 0.0625f, acc[1] * 0.0625f, acc[2] * 0.0625f, acc[3] * 0.0625f};
    float4 o2 = {acc[4] * 0.0625f, acc[5] * 0.0625f, acc[6] * 0.0625f, acc[7] * 0.0625f};
    *(float4*)d = o1;
    *(float4*)(d + 4) = o2;
}

// ============ o-proj: 64x128 tiles, 256 blocks ============
__global__ __launch_bounds__(256, 2)
void gemm_o64(const ushort_t* __restrict__ A, const ushort_t* __restrict__ B,
              const float* __restrict__ bias, float* __restrict__ Y)
{
    __shared__ ushort_t As[64 * 64];
    __shared__ ushort_t Bs[128 * 64];
    const int tid = threadIdx.x;
    const int wave = tid >> 6, lane = tid & 63;
    const int ln = lane & 15, lq = lane >> 4;
    const int row0 = blockIdx.y * 64, col0 = blockIdx.x * 128;
    const int wm = wave & 1, wn = wave >> 1;
    const int cswz = (lane & 7) ^ ((lane >> 3) & 7);
    const int mrl = lane >> 3;

    f32x4 zero = {0.f, 0.f, 0.f, 0.f};
    f32x4 acc[2][4];
#pragma unroll
    for (int i = 0; i < 2; ++i)
#pragma unroll
        for (int j = 0; j < 4; ++j) acc[i][j] = zero;

    for (int kk = 0; kk < 1024; kk += 64) {
        __syncthreads();
#pragma unroll
        for (int j = 0; j < 2; ++j) {
            const int mr = (wave * 2 + j) * 8 + mrl;
            gload_lds16(A + (size_t)(row0 + mr) * 1024 + kk + cswz * 8,
                        (void*)(As + (wave * 2 + j) * 512));
        }
#pragma unroll
        for (int j = 0; j < 4; ++j) {
            const int mr = (wave * 4 + j) * 8 + mrl;
            gload_lds16(B + (size_t)(col0 + mr) * 1024 + kk + cswz * 8,
                        (void*)(Bs + (wave * 4 + j) * 512));
        }
        __syncthreads();
#pragma unroll
        for (int sub = 0; sub < 2; ++sub) {
            short8 af[2], bfv[4];
#pragma unroll
            for (int i = 0; i < 2; ++i) {
                const int ml = wm * 32 + i * 16 + ln;
                af[i] = *(const short8*)(As + ml * 64 + (((sub * 4 + lq) ^ (ml & 7)) * 8));
            }
#pragma unroll
            for (int j = 0; j < 4; ++j) {
                const int nl = wn * 64 + j * 16 + ln;
                bfv[j] = *(const short8*)(Bs + nl * 64 + (((sub * 4 + lq) ^ (nl & 7)) * 8));
            }
#pragma unroll
            for (int i = 0; i < 2; ++i)
#pragma unroll
                for (int j = 0; j < 4; ++j)
                    acc[i][j] = __builtin_amdgcn_mfma_f32_16x16x32_bf16(af[i], bfv[j], acc[i][j], 0, 0, 0);
        }
    }

#pragma unroll
    for (int i = 0; i < 2; ++i) {
#pragma unroll
        for (int r = 0; r < 4; ++r) {
            const int row = row0 + wm * 32 + i * 16 + lq * 4 + r;
#pragma unroll
            for (int j = 0; j < 4; ++j) {
                const int col = col0 + wn * 64 + j * 16 + ln;
                Y[(size_t)row * 1024 + col] = acc[i][j][r] + bias[col];
            }
        }
    }
}

// ============================ launch ============================
extern "C" void kernel_launch(void* const* d_in, const int* in_sizes, int n_in,
                              void* d_out, int out_size, void* d_ws, size_t ws_size,
                              hipStream_t stream)
{
    const float* query = (const float*)d_in[0];
    const float* mod1  = (const float*)d_in[1];
    const float* mod2  = (const float*)d_in[2];
    const float* q_w  = (const float*)d_in[3];  const float* q_b  = (const float*)d_in[4];
    const float* k1_w = (const float*)d_in[5];  const float* k1_b = (const float*)d_in[6];
    const float* k2_w = (const float*)d_in[7];  const float* k2_b = (const float*)d_in[8];
    const float* v1_w = (const float*)d_in[9];  const float* v1_b = (const float*)d_in[10];
    const float* v2_w = (const float*)d_in[11]; const float* v2_b = (const float*)d_in[12];
    const float* g1_w = (const float*)d_in[13]; const float* g1_b = (const float*)d_in[14];
    const float* g2_w = (const float*)d_in[15]; const float* g2_b = (const float*)d_in[16];
    const float* o_w  = (const float*)d_in[17]; const float* o_b  = (const float*)d_in[18];
    float* out = (float*)d_out;

    const size_t MB = 1u << 20;
    char* w = (char*)d_ws;
    // persistent region (0..78 MB)
    ushort_t* Wqg  = (ushort_t*)(w + 0 * MB);    // 6 MB [q|g1|g2]^T
    ushort_t* Wkv1 = (ushort_t*)(w + 6 * MB);    // 4 MB [k1|v1]^T
    ushort_t* Wkv2 = (ushort_t*)(w + 10 * MB);   // 4 MB [k2|v2]^T
    ushort_t* Wo   = (ushort_t*)(w + 14 * MB);   // 2 MB
    ushort_t* Wk1l = (ushort_t*)(w + 16 * MB);   // 2 MB
    ushort_t* Wk2l = (ushort_t*)(w + 18 * MB);   // 2 MB
    ushort_t* qx   = (ushort_t*)(w + 20 * MB);   // 4 MB; dead after mega-GEMM
    ushort_t* tmpb = qx;                         // reuse for gated PV output
    ushort_t* Qb   = (ushort_t*)(w + 24 * MB);   // 4 MB
    ushort_t* K1b  = (ushort_t*)(w + 28 * MB);   // 8 MB
    ushort_t* K2b  = (ushort_t*)(w + 36 * MB);   // 8 MB
    ushort_t* V1t  = (ushort_t*)(w + 44 * MB);   // 8 MB
    ushort_t* V2t  = (ushort_t*)(w + 52 * MB);   // 8 MB
    ushort_t* G1b  = (ushort_t*)(w + 60 * MB);   // 4 MB bf16 gates
    ushort_t* G2b  = (ushort_t*)(w + 64 * MB);   // 4 MB
    float* ll = (float*)(w + 68 * MB);                   // 128 KB
    float* vv = (float*)(w + 68 * MB + 256 * 1024);      // 256 KB
    float* aa = (float*)(w + 68 * MB + 512 * 1024);
    float* va = (float*)(w + 68 * MB + 768 * 1024);
    float* invS = (float*)(w + 69 * MB);         // 128 KB per-row inv softmax sums
    // transient region 78..158 MB (overlays, all dead before flash):
    ushort_t* attn = (ushort_t*)(w + 78 * MB);   // 64 MB bf16 unnormalized p
    ushort_t* m1h = (ushort_t*)(w + 78 * MB);    // 8 MB  (dead after mega-GEMM)
    ushort_t* m2h = (ushort_t*)(w + 86 * MB);    // 8 MB
    ushort_t* m1l = (ushort_t*)(w + 94 * MB);    // 8 MB
    ushort_t* m2l = (ushort_t*)(w + 102 * MB);   // 8 MB
    float* K1f = (float*)(w + 110 * MB);         // 16 MB (dead after prep)
    float* K2f = (float*)(w + 126 * MB);         // 16 MB
    ushort_t* V1b = (ushort_t*)(w + 142 * MB);   // 8 MB (dead after prep)
    ushort_t* V2b = (ushort_t*)(w + 150 * MB);   // 8 MB

    // 1) fused casts
    CastArgs ca;
    ca.q = query; ca.m1 = mod1; ca.m2 = mod2;
    ca.qx = qx; ca.m1h = m1h; ca.m1l = m1l; ca.m2h = m2h; ca.m2l = m2l;
    const float* srcs[8] = {q_w, g1_w, g2_w, k1_w, v1_w, k2_w, v2_w, o_w};
    ushort_t* his[8] = {Wqg, Wqg + (size_t)1024 * 1024, Wqg + (size_t)2048 * 1024,
                        Wkv1, Wkv1 + (size_t)1024 * 1024, Wkv2, Wkv2 + (size_t)1024 * 1024, Wo};
    ushort_t* los[8] = {nullptr, nullptr, nullptr, Wk1l, nullptr, Wk2l, nullptr, nullptr};
    for (int i = 0; i < 8; ++i) { ca.wsrc[i] = srcs[i]; ca.whi[i] = his[i]; ca.wlo[i] = los[i]; }
    casts_kernel<<<7168, 256, 0, stream>>>(ca);

    // 2) all projections, one balanced launch
    MegaArgs ma;
    ma.qx = qx; ma.m1h = m1h; ma.m1l = m1l; ma.m2h = m2h; ma.m2l = m2l;
    ma.Wqg = Wqg; ma.Wkv1 = Wkv1; ma.Wkv2 = Wkv2; ma.Wk1l = Wk1l; ma.Wk2l = Wk2l;
    ma.q_b = q_b; ma.k1_b = k1_b; ma.k2_b = k2_b; ma.v1_b = v1_b; ma.v2_b = v2_b;
    ma.g1_b = g1_b; ma.g2_b = g2_b;
    ma.K1f = K1f; ma.K2f = K2f; ma.V1b = V1b; ma.V2b = V2b;
    ma.Qb = Qb; ma.G1b = G1b; ma.G2b = G2b;
    mega_gemm<<<1408, 256, 0, stream>>>(ma);

    // 3) fused prep (K norms+cast, Q norms, V transpose)
    prep_kernel<<<26624, 256, 0, stream>>>(K1f, K2f, K1b, K2b, vv, aa, va,
                                           Qb, ll, V1b, V2b, V1t, V2t);

    // 4) single-pass flash attention
    flash_attn<<<dim3(4, 64), 512, 0, stream>>>(Qb, K1b, K2b, V1t, V2t,
                                                ll, vv, aa, va, G1b, G2b,
                                                attn, invS, tmpb);

    // 5-6) head average (applies invS) + output projection
    head_avg_kernel<<<1024, 256, 0, stream>>>(attn, invS, out + (size_t)LQ * NB * EDIM);
    gemm_o64<<<dim3(8, 32), 256, 0, stream>>>(tmpb, Wo, o_b, out);
}